// Round 1
// baseline (110.236 us; speedup 1.0000x reference)
//
#include <hip/hip_runtime.h>
#include <math.h>

#define BB 4
#define CC 64
#define HH 224
#define WW 224
#define HWW (HH*WW)
#define SS 257
#define IH 222
#define IW 222
#define NPIX (IH*IW)

// Monotone float -> uint32 key (order-preserving), for integer atomicMax.
__device__ __forceinline__ unsigned fkey(float f) {
    unsigned u = __float_as_uint(f);
    return (u & 0x80000000u) ? ~u : (u | 0x80000000u);
}
__device__ __forceinline__ float funkey(unsigned k) {
    return (k & 0x80000000u) ? __uint_as_float(k & 0x7FFFFFFFu) : __uint_as_float(~k);
}
#define SENT 0x007FFFFFu  // fkey(-inf): empty-segment sentinel

// ---------------- segment-max pooling ----------------
// grid (C, B, 3); block 512. Each block owns one (map z, batch b, channel c)
// slice of enc[3][B][C][S]. LDS atomics only; exclusive global writes.
__global__ __launch_bounds__(512) void pool_kernel(
    const float* __restrict__ fT, const float* __restrict__ fR,
    const float* __restrict__ fV,
    const int* __restrict__ labT, const int* __restrict__ labR,
    float* __restrict__ enc)
{
    __shared__ unsigned seg[SS];
    const int c = blockIdx.x, b = blockIdx.y, z = blockIdx.z;
    const float* src = (z == 0) ? fT : (z == 1) ? fR : fV;
    const int*   lab = (z == 0) ? labT : labR;

    for (int i = threadIdx.x; i < SS; i += 512) seg[i] = SENT;
    __syncthreads();

    const float* sp = src + (size_t)(b * CC + c) * HWW;
    const int*   lp = lab + (size_t)b * HWW;
    for (int pi = threadIdx.x; pi < NPIX; pi += 512) {
        int h = pi / IW;
        int w = pi - h * IW;
        int off = (h + 1) * WW + (w + 1);
        float v = sp[off];
        int   l = lp[off];
        atomicMax(&seg[l], fkey(v));
    }
    __syncthreads();

    float* op = enc + (size_t)((z * BB + b) * CC + c) * SS;
    for (int i = threadIdx.x; i < SS; i += 512) {
        unsigned k = seg[i];
        op[i] = (k == SENT) ? 0.0f : funkey(k);   // empty segments -> 0
    }
}

// ---------------- n = max(label)+1 over FULL mask ----------------
__global__ void init_n(int* nmax) { if (threadIdx.x < 2 * BB) nmax[threadIdx.x] = 0; }

__global__ __launch_bounds__(256) void nmax_kernel(
    const int* __restrict__ labT, const int* __restrict__ labR, int* __restrict__ nmax)
{
    const int b = blockIdx.y, which = blockIdx.z;
    const int* lp = (which ? labR : labT) + (size_t)b * HWW;
    int m = -1;
    for (int i = blockIdx.x * blockDim.x + threadIdx.x; i < HWW; i += gridDim.x * blockDim.x)
        m = max(m, lp[i]);
    for (int o = 32; o; o >>= 1) m = max(m, __shfl_xor(m, o, 64));
    __shared__ int sred[4];
    if ((threadIdx.x & 63) == 0) sred[threadIdx.x >> 6] = m;
    __syncthreads();
    if (threadIdx.x == 0) {
        int mm = max(max(sred[0], sred[1]), max(sred[2], sred[3]));
        atomicMax(&nmax[which * BB + b], mm + 1);
    }
}

// ---------------- chan_norm + W@x + b -> q/k/v in [3][B][S][C] ----------------
// grid (ceil(S/8), B, 3); block 512 = 8 waves, one column per wave, lane = channel.
__global__ __launch_bounds__(512) void qkv_kernel(
    const float* __restrict__ enc,
    const float* __restrict__ Wq, const float* __restrict__ bq,
    const float* __restrict__ Wk, const float* __restrict__ bk,
    const float* __restrict__ Wv, const float* __restrict__ bv,
    float* __restrict__ qkv)
{
    const int z = blockIdx.z, b = blockIdx.y;
    const int wid = threadIdx.x >> 6, lane = threadIdx.x & 63;
    const int n = blockIdx.x * 8 + wid;
    if (n >= SS) return;

    const float* Wm = (z == 0) ? Wq : (z == 1) ? Wk : Wv;
    const float* bm = (z == 0) ? bq : (z == 1) ? bk : bv;
    // q <- enc_t (z=0), k <- enc_r (z=1), v <- enc_v (z=2); enc is [3][B][C][S]
    const float* ep = enc + (size_t)((z * BB + b) * CC) * SS + n;

    float x = ep[(size_t)lane * SS];
    if (z != 2) {  // chan_norm for q,k inputs
        float s = x;
        for (int o = 32; o; o >>= 1) s += __shfl_xor(s, o, 64);
        float xm = x - s * (1.0f / 64.0f);
        float s2 = xm * xm;
        for (int o = 32; o; o >>= 1) s2 += __shfl_xor(s2, o, 64);
        x = xm / (sqrtf(s2) + 1e-5f);
    }
    float acc = bm[lane];
    #pragma unroll
    for (int cI = 0; cI < 64; ++cI) {
        float xc = __shfl(x, cI, 64);
        acc = fmaf(Wm[lane * 64 + cI], xc, acc);
    }
    qkv[(size_t)((z * BB + b) * SS + n) * CC + lane] = acc;
}

// ---------------- attention row + PV ----------------
// grid (S, B); block 256. One (b, n) row per block.
__global__ __launch_bounds__(256) void attn_kernel(
    const float* __restrict__ qkv, const int* __restrict__ nmax,
    float* __restrict__ wg)
{
    const int n = blockIdx.x, b = blockIdx.y, t = threadIdx.x;
    __shared__ float qs[CC];
    __shared__ float sim[512];
    __shared__ float red[256];
    __shared__ float pv[4][64];

    const int nT = nmax[b], nR = nmax[BB + b];
    float* wp = wg + (size_t)(b * SS + n) * CC;
    if (n >= nT) {                       // tmask zeroes this row
        if (t < CC) wp[t] = 0.0f;
        return;
    }
    const float* q = qkv + (size_t)(0 * BB + b) * SS * CC;
    const float* k = qkv + (size_t)(1 * BB + b) * SS * CC;
    const float* v = qkv + (size_t)(2 * BB + b) * SS * CC;

    if (t < CC) qs[t] = q[(size_t)n * CC + t];
    sim[t] = -INFINITY;
    sim[t + 256] = -INFINITY;
    __syncthreads();

    for (int m = t; m < SS; m += 256) {
        float s = -INFINITY;
        if (m < nR) {
            const float4* kr = (const float4*)(k + (size_t)m * CC);
            float acc = 0.0f;
            #pragma unroll
            for (int i = 0; i < 16; ++i) {
                float4 kv = kr[i];
                acc += qs[4*i+0]*kv.x + qs[4*i+1]*kv.y + qs[4*i+2]*kv.z + qs[4*i+3]*kv.w;
            }
            s = acc * 100.0f;            // /0.01 temperature
        }
        sim[m] = s;
    }
    __syncthreads();

    // row max
    red[t] = fmaxf(sim[t], sim[t + 256]);
    __syncthreads();
    for (int s = 128; s > 0; s >>= 1) {
        if (t < s) red[t] = fmaxf(red[t], red[t + s]);
        __syncthreads();
    }
    const float mx = red[0];
    __syncthreads();

    // exp + row sum
    float psum = 0.0f;
    for (int m = t; m < SS; m += 256) {
        float e = expf(sim[m] - mx);     // exp(-inf - mx) = 0 for masked cols
        sim[m] = e;
        psum += e;
    }
    red[t] = psum;
    __syncthreads();
    for (int s = 128; s > 0; s >>= 1) {
        if (t < s) red[t] += red[t + s];
        __syncthreads();
    }
    const float rdenom = 1.0f / red[0];

    // PV: wg[b, n, c] = (sum_m e[m] * v[b, m, c]) * rdenom
    const int g = t >> 6, c = t & 63;
    float acc = 0.0f;
    for (int m = g; m < SS; m += 4)
        acc = fmaf(sim[m], v[(size_t)m * CC + c], acc);
    pv[g][c] = acc;
    __syncthreads();
    if (t < CC)
        wp[t] = (pv[0][t] + pv[1][t] + pv[2][t] + pv[3][t]) * rdenom;
}

// ---------------- unpool gather ----------------
// one thread per (b, hw); reads 256B wg row for its label, scatters 64 channels
// (coalesced across threads for each c).
__global__ __launch_bounds__(256) void unpool_kernel(
    const float* __restrict__ wg, const int* __restrict__ labT,
    float* __restrict__ out)
{
    const int idx = blockIdx.x * 256 + threadIdx.x;  // over B*HW
    if (idx >= BB * HWW) return;
    const int b = idx / HWW, hw = idx - b * HWW;
    const int l = labT[idx];
    const float4* row = (const float4*)(wg + (size_t)(b * SS + l) * CC);
    float* op = out + (size_t)b * CC * HWW + hw;
    #pragma unroll
    for (int i = 0; i < 16; ++i) {
        float4 r = row[i];
        op[(size_t)(4*i+0) * HWW] = r.x;
        op[(size_t)(4*i+1) * HWW] = r.y;
        op[(size_t)(4*i+2) * HWW] = r.z;
        op[(size_t)(4*i+3) * HWW] = r.w;
    }
}

extern "C" void kernel_launch(void* const* d_in, const int* in_sizes, int n_in,
                              void* d_out, int out_size, void* d_ws, size_t ws_size,
                              hipStream_t stream) {
    (void)in_sizes; (void)n_in; (void)out_size; (void)ws_size;
    const float* fT  = (const float*)d_in[0];
    const float* fR  = (const float*)d_in[1];
    const float* fV  = (const float*)d_in[2];
    const float* Wq  = (const float*)d_in[3];
    const float* bq  = (const float*)d_in[4];
    const float* Wk  = (const float*)d_in[5];
    const float* bk  = (const float*)d_in[6];
    const float* Wv  = (const float*)d_in[7];
    const float* bv  = (const float*)d_in[8];
    const int* labT  = (const int*)d_in[9];
    const int* labR  = (const int*)d_in[10];
    float* out = (float*)d_out;

    // workspace layout (all 16B-aligned)
    float* enc  = (float*)d_ws;                   // [3][B][C][S]
    float* qkv  = enc + 3 * BB * CC * SS;         // [3][B][S][C]
    float* wg   = qkv + 3 * BB * CC * SS;         // [B][S][C]
    int*   nmax = (int*)(wg + BB * CC * SS);      // [2][B]

    init_n<<<1, 64, 0, stream>>>(nmax);
    pool_kernel<<<dim3(CC, BB, 3), 512, 0, stream>>>(fT, fR, fV, labT, labR, enc);
    nmax_kernel<<<dim3(8, BB, 2), 256, 0, stream>>>(labT, labR, nmax);
    qkv_kernel<<<dim3((SS + 7) / 8, BB, 3), 512, 0, stream>>>(enc, Wq, bq, Wk, bk, Wv, bv, qkv);
    attn_kernel<<<dim3(SS, BB), 256, 0, stream>>>(qkv, nmax, wg);
    unpool_kernel<<<(BB * HWW + 255) / 256, 256, 0, stream>>>(wg, labT, out);
}

// Round 2
// 90.095 us; speedup vs baseline: 1.2236x; 1.2236x over previous
//
#include <hip/hip_runtime.h>
#include <math.h>

#define BB 4
#define CC 64
#define HH 224
#define WW 224
#define HWW (HH*WW)
#define SS 257
#define IH 222
#define IW 222
// full-row float4 groups: rows 1..222 (222 rows), 56 float4-groups per row
#define NG (222*56)

// Monotone float -> uint32 key (order-preserving), for integer atomicMax.
__device__ __forceinline__ unsigned fkey(float f) {
    unsigned u = __float_as_uint(f);
    return (u & 0x80000000u) ? ~u : (u | 0x80000000u);
}
__device__ __forceinline__ float funkey(unsigned k) {
    return (k & 0x80000000u) ? __uint_as_float(k & 0x7FFFFFFFu) : __uint_as_float(~k);
}
#define SENT 0x007FFFFFu  // fkey(-inf): empty-segment sentinel

// ---------------- segment-max pooling ----------------
// grid (C, B, 3); block 512. Each block owns one (map z, batch b, channel c)
// slice of enc[3][B][C][S]. Vectorized float4/int4 loads over FULL 224-wide
// rows (aligned); border columns masked per-lane. LDS atomics only.
__global__ __launch_bounds__(512) void pool_kernel(
    const float* __restrict__ fT, const float* __restrict__ fR,
    const float* __restrict__ fV,
    const int* __restrict__ labT, const int* __restrict__ labR,
    float* __restrict__ enc)
{
    __shared__ unsigned seg[SS];
    const int c = blockIdx.x, b = blockIdx.y, z = blockIdx.z;
    const float* src = (z == 0) ? fT : (z == 1) ? fR : fV;
    const int*   lab = (z == 0) ? labT : labR;

    for (int i = threadIdx.x; i < SS; i += 512) seg[i] = SENT;
    __syncthreads();

    const float4* sp4 = (const float4*)(src + (size_t)(b * CC + c) * HWW);
    const int4*   lp4 = (const int4*)(lab + (size_t)b * HWW);

    // gi in [0, NG): h = gi/56 -> image row h+1; g = gi%56 -> cols 4g..4g+3
    auto body = [&](int gi) {
        int h = gi / 56;
        int g = gi - h * 56;
        int idx4 = (h + 1) * 56 + g;          // row stride = 56 float4s
        float4 v = sp4[idx4];
        int4   l = lp4[idx4];
        if (g != 0)  atomicMax(&seg[l.x], fkey(v.x));   // skip w==0
        atomicMax(&seg[l.y], fkey(v.y));
        atomicMax(&seg[l.z], fkey(v.z));
        if (g != 55) atomicMax(&seg[l.w], fkey(v.w));   // skip w==223
    };

    int gi = threadIdx.x;
    #pragma unroll 4
    for (int it = 0; it < NG / 512; ++it, gi += 512)    // 24 constant iters
        body(gi);
    if (gi < NG) body(gi);                              // tail (144 threads)

    __syncthreads();
    float* op = enc + (size_t)((z * BB + b) * CC + c) * SS;
    for (int i = threadIdx.x; i < SS; i += 512) {
        unsigned k = seg[i];
        op[i] = (k == SENT) ? 0.0f : funkey(k);   // empty segments -> 0
    }
}

// ---------------- n = max(label)+1 over FULL mask ----------------
// grid 8 = [which][b]; block 1024; direct write, no init/atomics.
__global__ __launch_bounds__(1024) void nmax_kernel(
    const int* __restrict__ labT, const int* __restrict__ labR, int* __restrict__ nmax)
{
    const int b = blockIdx.x & (BB - 1), which = blockIdx.x >> 2;
    const int4* lp = (const int4*)((which ? labR : labT) + (size_t)b * HWW);
    int m = -1;
    for (int i = threadIdx.x; i < HWW / 4; i += 1024) {
        int4 v = lp[i];
        m = max(max(m, v.x), max(v.y, max(v.z, v.w)));
    }
    for (int o = 32; o; o >>= 1) m = max(m, __shfl_xor(m, o, 64));
    __shared__ int sred[16];
    if ((threadIdx.x & 63) == 0) sred[threadIdx.x >> 6] = m;
    __syncthreads();
    if (threadIdx.x < 16) {
        m = sred[threadIdx.x];
        #pragma unroll
        for (int o = 8; o; o >>= 1) m = max(m, __shfl_xor(m, o, 16));
        if (threadIdx.x == 0) nmax[blockIdx.x] = m + 1;
    }
}

// ---------------- chan_norm + W@x + b -> q/k/v in [3][B][S][C] ----------------
// grid (ceil(S/8), B, 3); block 512 = 8 waves, one column per wave, lane = channel.
__global__ __launch_bounds__(512) void qkv_kernel(
    const float* __restrict__ enc,
    const float* __restrict__ Wq, const float* __restrict__ bq,
    const float* __restrict__ Wk, const float* __restrict__ bk,
    const float* __restrict__ Wv, const float* __restrict__ bv,
    float* __restrict__ qkv)
{
    const int z = blockIdx.z, b = blockIdx.y;
    const int wid = threadIdx.x >> 6, lane = threadIdx.x & 63;
    const int n = blockIdx.x * 8 + wid;
    if (n >= SS) return;

    const float* Wm = (z == 0) ? Wq : (z == 1) ? Wk : Wv;
    const float* bm = (z == 0) ? bq : (z == 1) ? bk : bv;
    const float* ep = enc + (size_t)((z * BB + b) * CC) * SS + n;

    float x = ep[(size_t)lane * SS];
    if (z != 2) {  // chan_norm for q,k inputs
        float s = x;
        for (int o = 32; o; o >>= 1) s += __shfl_xor(s, o, 64);
        float xm = x - s * (1.0f / 64.0f);
        float s2 = xm * xm;
        for (int o = 32; o; o >>= 1) s2 += __shfl_xor(s2, o, 64);
        x = xm / (sqrtf(s2) + 1e-5f);
    }
    float acc = bm[lane];
    #pragma unroll
    for (int cI = 0; cI < 64; ++cI) {
        float xc = __shfl(x, cI, 64);
        acc = fmaf(Wm[lane * 64 + cI], xc, acc);
    }
    qkv[(size_t)((z * BB + b) * SS + n) * CC + lane] = acc;
}

// ---------------- attention row + PV ----------------
// grid (S, B); block 256. One (b, n) row per block.
__global__ __launch_bounds__(256) void attn_kernel(
    const float* __restrict__ qkv, const int* __restrict__ nmax,
    float* __restrict__ wg)
{
    const int n = blockIdx.x, b = blockIdx.y, t = threadIdx.x;
    __shared__ float qs[CC];
    __shared__ float sim[512];
    __shared__ float red[256];
    __shared__ float pv[4][64];

    const int nT = nmax[b], nR = nmax[BB + b];
    float* wp = wg + (size_t)(b * SS + n) * CC;
    if (n >= nT) {                       // tmask zeroes this row
        if (t < CC) wp[t] = 0.0f;
        return;
    }
    const float* q = qkv + (size_t)(0 * BB + b) * SS * CC;
    const float* k = qkv + (size_t)(1 * BB + b) * SS * CC;
    const float* v = qkv + (size_t)(2 * BB + b) * SS * CC;

    if (t < CC) qs[t] = q[(size_t)n * CC + t];
    sim[t] = -INFINITY;
    sim[t + 256] = -INFINITY;
    __syncthreads();

    for (int m = t; m < SS; m += 256) {
        float s = -INFINITY;
        if (m < nR) {
            const float4* kr = (const float4*)(k + (size_t)m * CC);
            float acc = 0.0f;
            #pragma unroll
            for (int i = 0; i < 16; ++i) {
                float4 kv = kr[i];
                acc += qs[4*i+0]*kv.x + qs[4*i+1]*kv.y + qs[4*i+2]*kv.z + qs[4*i+3]*kv.w;
            }
            s = acc * 100.0f;            // /0.01 temperature
        }
        sim[m] = s;
    }
    __syncthreads();

    red[t] = fmaxf(sim[t], sim[t + 256]);
    __syncthreads();
    for (int s = 128; s > 0; s >>= 1) {
        if (t < s) red[t] = fmaxf(red[t], red[t + s]);
        __syncthreads();
    }
    const float mx = red[0];
    __syncthreads();

    float psum = 0.0f;
    for (int m = t; m < SS; m += 256) {
        float e = expf(sim[m] - mx);     // exp(-inf - mx) = 0 for masked cols
        sim[m] = e;
        psum += e;
    }
    red[t] = psum;
    __syncthreads();
    for (int s = 128; s > 0; s >>= 1) {
        if (t < s) red[t] += red[t + s];
        __syncthreads();
    }
    const float rdenom = 1.0f / red[0];

    const int g = t >> 6, c = t & 63;
    float acc = 0.0f;
    for (int m = g; m < SS; m += 4)
        acc = fmaf(sim[m], v[(size_t)m * CC + c], acc);
    pv[g][c] = acc;
    __syncthreads();
    if (t < CC)
        wp[t] = (pv[0][t] + pv[1][t] + pv[2][t] + pv[3][t]) * rdenom;
}

// ---------------- unpool gather ----------------
__global__ __launch_bounds__(256) void unpool_kernel(
    const float* __restrict__ wg, const int* __restrict__ labT,
    float* __restrict__ out)
{
    const int idx = blockIdx.x * 256 + threadIdx.x;  // over B*HW
    if (idx >= BB * HWW) return;
    const int b = idx / HWW, hw = idx - b * HWW;
    const int l = labT[idx];
    const float4* row = (const float4*)(wg + (size_t)(b * SS + l) * CC);
    float* op = out + (size_t)b * CC * HWW + hw;
    #pragma unroll
    for (int i = 0; i < 16; ++i) {
        float4 r = row[i];
        op[(size_t)(4*i+0) * HWW] = r.x;
        op[(size_t)(4*i+1) * HWW] = r.y;
        op[(size_t)(4*i+2) * HWW] = r.z;
        op[(size_t)(4*i+3) * HWW] = r.w;
    }
}

extern "C" void kernel_launch(void* const* d_in, const int* in_sizes, int n_in,
                              void* d_out, int out_size, void* d_ws, size_t ws_size,
                              hipStream_t stream) {
    (void)in_sizes; (void)n_in; (void)out_size; (void)ws_size;
    const float* fT  = (const float*)d_in[0];
    const float* fR  = (const float*)d_in[1];
    const float* fV  = (const float*)d_in[2];
    const float* Wq  = (const float*)d_in[3];
    const float* bq  = (const float*)d_in[4];
    const float* Wk  = (const float*)d_in[5];
    const float* bk  = (const float*)d_in[6];
    const float* Wv  = (const float*)d_in[7];
    const float* bv  = (const float*)d_in[8];
    const int* labT  = (const int*)d_in[9];
    const int* labR  = (const int*)d_in[10];
    float* out = (float*)d_out;

    float* enc  = (float*)d_ws;                   // [3][B][C][S]
    float* qkv  = enc + 3 * BB * CC * SS;         // [3][B][S][C]
    float* wg   = qkv + 3 * BB * CC * SS;         // [B][S][C]
    int*   nmax = (int*)(wg + BB * CC * SS);      // [2][B]

    nmax_kernel<<<8, 1024, 0, stream>>>(labT, labR, nmax);
    pool_kernel<<<dim3(CC, BB, 3), 512, 0, stream>>>(fT, fR, fV, labT, labR, enc);
    qkv_kernel<<<dim3((SS + 7) / 8, BB, 3), 512, 0, stream>>>(enc, Wq, bq, Wk, bk, Wv, bv, qkv);
    attn_kernel<<<dim3(SS, BB), 256, 0, stream>>>(qkv, nmax, wg);
    unpool_kernel<<<(BB * HWW + 255) / 256, 256, 0, stream>>>(wg, labT, out);
}

// Round 3
// 82.235 us; speedup vs baseline: 1.3405x; 1.0956x over previous
//
#include <hip/hip_runtime.h>
#include <math.h>

#define BB 4
#define CC 64
#define HH 224
#define WW 224
#define HWW (HH*WW)
#define SS 257
#define IH 222
#define IW 222
// full-row float4 groups: rows 1..222 (222 rows), 56 float4-groups per row
#define NG (222*56)
#define NI ((NG + 511) / 512)   // 25 guarded iterations

// Monotone float -> uint32 key (order-preserving), for integer atomicMax.
__device__ __forceinline__ unsigned fkey(float f) {
    unsigned u = __float_as_uint(f);
    return (u & 0x80000000u) ? ~u : (u | 0x80000000u);
}
__device__ __forceinline__ float funkey(unsigned k) {
    return (k & 0x80000000u) ? __uint_as_float(k & 0x7FFFFFFFu) : __uint_as_float(~k);
}
#define SENT 0x007FFFFFu  // fkey(-inf): empty-segment sentinel

// ---------------- segment-max pooling (+ folded nmax) ----------------
// grid (C, B, 3); block 512. Each block owns one (map z, batch b, channel c)
// slice of enc[3][B][C][S]. Key change vs R2: ds_read check before atomic —
// random data beats the running max only ~1.5K times per 49K pixels, so the
// serialized LDS-atomic pipe (the measured 59us floor) drops out. Stale reads
// are <= true max, so skipping on (key <= stale) is race-safe.
// Blocks with c==0 && z<2 also reduce max(label) over the FULL mask -> nmax.
__global__ __launch_bounds__(512) void pool_kernel(
    const float* __restrict__ fT, const float* __restrict__ fR,
    const float* __restrict__ fV,
    const int* __restrict__ labT, const int* __restrict__ labR,
    float* __restrict__ enc, int* __restrict__ nmax)
{
    __shared__ unsigned seg[SS];
    __shared__ int wmax[8];
    const int c = blockIdx.x, b = blockIdx.y, z = blockIdx.z;
    const float* src = (z == 0) ? fT : (z == 1) ? fR : fV;
    const int*   lab = (z == 0) ? labT : labR;
    const bool do_nmax = (c == 0) && (z < 2);

    for (int i = threadIdx.x; i < SS; i += 512) seg[i] = SENT;
    __syncthreads();

    const float4* sp4 = (const float4*)(src + (size_t)(b * CC + c) * HWW);
    const int*    lp  = lab + (size_t)b * HWW;
    const int4*   lp4 = (const int4*)lp;

    int lmax = -1;

    // depth-1 software pipeline over guarded iterations
    int gi = threadIdx.x;
    bool act = gi < NG;
    float4 v = {}; int4 l = {}; int curg = 0;
    {
        int h = gi / 56; int g = gi - h * 56; curg = g;
        if (act) { int idx4 = (h + 1) * 56 + g; v = sp4[idx4]; l = lp4[idx4]; }
    }
    for (int it = 0; it < NI; ++it) {
        // prefetch next
        int gin = gi + 512;
        bool actn = gin < NG;
        float4 vn = {}; int4 ln = {}; int gn = 0;
        if (actn) {
            int hn = gin / 56; gn = gin - hn * 56;
            int idx4 = (hn + 1) * 56 + gn;
            vn = sp4[idx4]; ln = lp4[idx4];
        }
        // process current
        if (act) {
            if (do_nmax)
                lmax = max(lmax, max(max(l.x, l.y), max(l.z, l.w)));
            unsigned kx = fkey(v.x), ky = fkey(v.y), kz = fkey(v.z), kw = fkey(v.w);
            if (curg != 0  && kx > seg[l.x]) atomicMax(&seg[l.x], kx);  // skip w==0
            if (ky > seg[l.y]) atomicMax(&seg[l.y], ky);
            if (kz > seg[l.z]) atomicMax(&seg[l.z], kz);
            if (curg != 55 && kw > seg[l.w]) atomicMax(&seg[l.w], kw);  // skip w==223
        }
        v = vn; l = ln; act = actn; gi = gin; curg = gn;
    }

    // nmax: interior rows are fully covered above (cols 0/223 included in the
    // vector loads); add rows 0 and 223 (448 px), then block-reduce.
    if (do_nmax && threadIdx.x < 448) {
        int t = threadIdx.x;
        int off = (t < 224) ? t : (223 * 224 + (t - 224));
        lmax = max(lmax, lp[off]);
    }
    #pragma unroll
    for (int o = 32; o; o >>= 1) lmax = max(lmax, __shfl_xor(lmax, o, 64));
    if ((threadIdx.x & 63) == 0) wmax[threadIdx.x >> 6] = lmax;
    __syncthreads();   // also drains all seg atomics

    if (do_nmax && threadIdx.x == 0) {
        int m = wmax[0];
        #pragma unroll
        for (int i = 1; i < 8; ++i) m = max(m, wmax[i]);
        nmax[z * BB + b] = m + 1;
    }

    float* op = enc + (size_t)((z * BB + b) * CC + c) * SS;
    for (int i = threadIdx.x; i < SS; i += 512) {
        unsigned k = seg[i];
        op[i] = (k == SENT) ? 0.0f : funkey(k);   // empty segments -> 0
    }
}

// ---------------- chan_norm + W@x + b -> q/k/v in [3][B][S][C] ----------------
// grid (ceil(S/8), B, 3); block 512 = 8 waves, one column per wave, lane = channel.
__global__ __launch_bounds__(512) void qkv_kernel(
    const float* __restrict__ enc,
    const float* __restrict__ Wq, const float* __restrict__ bq,
    const float* __restrict__ Wk, const float* __restrict__ bk,
    const float* __restrict__ Wv, const float* __restrict__ bv,
    float* __restrict__ qkv)
{
    const int z = blockIdx.z, b = blockIdx.y;
    const int wid = threadIdx.x >> 6, lane = threadIdx.x & 63;
    const int n = blockIdx.x * 8 + wid;
    if (n >= SS) return;

    const float* Wm = (z == 0) ? Wq : (z == 1) ? Wk : Wv;
    const float* bm = (z == 0) ? bq : (z == 1) ? bk : bv;
    const float* ep = enc + (size_t)((z * BB + b) * CC) * SS + n;

    float x = ep[(size_t)lane * SS];
    if (z != 2) {  // chan_norm for q,k inputs
        float s = x;
        for (int o = 32; o; o >>= 1) s += __shfl_xor(s, o, 64);
        float xm = x - s * (1.0f / 64.0f);
        float s2 = xm * xm;
        for (int o = 32; o; o >>= 1) s2 += __shfl_xor(s2, o, 64);
        x = xm / (sqrtf(s2) + 1e-5f);
    }
    float acc = bm[lane];
    #pragma unroll
    for (int cI = 0; cI < 64; ++cI) {
        float xc = __shfl(x, cI, 64);
        acc = fmaf(Wm[lane * 64 + cI], xc, acc);
    }
    qkv[(size_t)((z * BB + b) * SS + n) * CC + lane] = acc;
}

// ---------------- attention row + PV ----------------
// grid (S, B); block 256. One (b, n) row per block.
__global__ __launch_bounds__(256) void attn_kernel(
    const float* __restrict__ qkv, const int* __restrict__ nmax,
    float* __restrict__ wg)
{
    const int n = blockIdx.x, b = blockIdx.y, t = threadIdx.x;
    __shared__ float qs[CC];
    __shared__ float sim[512];
    __shared__ float red[256];
    __shared__ float pv[4][64];

    const int nT = nmax[b], nR = nmax[BB + b];
    float* wp = wg + (size_t)(b * SS + n) * CC;
    if (n >= nT) {                       // tmask zeroes this row
        if (t < CC) wp[t] = 0.0f;
        return;
    }
    const float* q = qkv + (size_t)(0 * BB + b) * SS * CC;
    const float* k = qkv + (size_t)(1 * BB + b) * SS * CC;
    const float* v = qkv + (size_t)(2 * BB + b) * SS * CC;

    if (t < CC) qs[t] = q[(size_t)n * CC + t];
    sim[t] = -INFINITY;
    sim[t + 256] = -INFINITY;
    __syncthreads();

    for (int m = t; m < SS; m += 256) {
        float s = -INFINITY;
        if (m < nR) {
            const float4* kr = (const float4*)(k + (size_t)m * CC);
            float acc = 0.0f;
            #pragma unroll
            for (int i = 0; i < 16; ++i) {
                float4 kv = kr[i];
                acc += qs[4*i+0]*kv.x + qs[4*i+1]*kv.y + qs[4*i+2]*kv.z + qs[4*i+3]*kv.w;
            }
            s = acc * 100.0f;            // /0.01 temperature
        }
        sim[m] = s;
    }
    __syncthreads();

    red[t] = fmaxf(sim[t], sim[t + 256]);
    __syncthreads();
    for (int s = 128; s > 0; s >>= 1) {
        if (t < s) red[t] = fmaxf(red[t], red[t + s]);
        __syncthreads();
    }
    const float mx = red[0];
    __syncthreads();

    float psum = 0.0f;
    for (int m = t; m < SS; m += 256) {
        float e = expf(sim[m] - mx);     // exp(-inf - mx) = 0 for masked cols
        sim[m] = e;
        psum += e;
    }
    red[t] = psum;
    __syncthreads();
    for (int s = 128; s > 0; s >>= 1) {
        if (t < s) red[t] += red[t + s];
        __syncthreads();
    }
    const float rdenom = 1.0f / red[0];

    const int g = t >> 6, c = t & 63;
    float acc = 0.0f;
    for (int m = g; m < SS; m += 4)
        acc = fmaf(sim[m], v[(size_t)m * CC + c], acc);
    pv[g][c] = acc;
    __syncthreads();
    if (t < CC)
        wp[t] = (pv[0][t] + pv[1][t] + pv[2][t] + pv[3][t]) * rdenom;
}

// ---------------- unpool gather ----------------
__global__ __launch_bounds__(256) void unpool_kernel(
    const float* __restrict__ wg, const int* __restrict__ labT,
    float* __restrict__ out)
{
    const int idx = blockIdx.x * 256 + threadIdx.x;  // over B*HW
    if (idx >= BB * HWW) return;
    const int b = idx / HWW, hw = idx - b * HWW;
    const int l = labT[idx];
    const float4* row = (const float4*)(wg + (size_t)(b * SS + l) * CC);
    float* op = out + (size_t)b * CC * HWW + hw;
    #pragma unroll
    for (int i = 0; i < 16; ++i) {
        float4 r = row[i];
        op[(size_t)(4*i+0) * HWW] = r.x;
        op[(size_t)(4*i+1) * HWW] = r.y;
        op[(size_t)(4*i+2) * HWW] = r.z;
        op[(size_t)(4*i+3) * HWW] = r.w;
    }
}

extern "C" void kernel_launch(void* const* d_in, const int* in_sizes, int n_in,
                              void* d_out, int out_size, void* d_ws, size_t ws_size,
                              hipStream_t stream) {
    (void)in_sizes; (void)n_in; (void)out_size; (void)ws_size;
    const float* fT  = (const float*)d_in[0];
    const float* fR  = (const float*)d_in[1];
    const float* fV  = (const float*)d_in[2];
    const float* Wq  = (const float*)d_in[3];
    const float* bq  = (const float*)d_in[4];
    const float* Wk  = (const float*)d_in[5];
    const float* bk  = (const float*)d_in[6];
    const float* Wv  = (const float*)d_in[7];
    const float* bv  = (const float*)d_in[8];
    const int* labT  = (const int*)d_in[9];
    const int* labR  = (const int*)d_in[10];
    float* out = (float*)d_out;

    float* enc  = (float*)d_ws;                   // [3][B][C][S]
    float* qkv  = enc + 3 * BB * CC * SS;         // [3][B][S][C]
    float* wg   = qkv + 3 * BB * CC * SS;         // [B][S][C]
    int*   nmax = (int*)(wg + BB * CC * SS);      // [2][B]

    pool_kernel<<<dim3(CC, BB, 3), 512, 0, stream>>>(fT, fR, fV, labT, labR, enc, nmax);
    qkv_kernel<<<dim3((SS + 7) / 8, BB, 3), 512, 0, stream>>>(enc, Wq, bq, Wk, bk, Wv, bv, qkv);
    attn_kernel<<<dim3(SS, BB), 256, 0, stream>>>(qkv, nmax, wg);
    unpool_kernel<<<(BB * HWW + 255) / 256, 256, 0, stream>>>(wg, labT, out);
}